// Round 13
// baseline (2840.605 us; speedup 1.0000x reference)
//
#include <hip/hip_runtime.h>
#include <hip/hip_bf16.h>

typedef unsigned short u16;
typedef unsigned int u32;
typedef unsigned long long u64;
typedef __attribute__((ext_vector_type(8))) short bf16x8;   // 8 bf16 (4 VGPRs)
typedef __attribute__((ext_vector_type(4))) float f32x4;

#define MFMA(a,b,c) __builtin_amdgcn_mfma_f32_16x16x32_bf16((a),(b),(c),0,0,0)
#define AGENT __HIP_MEMORY_SCOPE_AGENT

// R13: MERGED-LAYER persistent wgs. 256 wgs x 256 thr; wg = (rowgroup rg of 16
// batch rows) x (16-col slice sl of H). Each wg computes BOTH GRU5 and GRU6
// for its tile; h5[t-1] is staged ONCE and feeds GRU5's U5-part AND GRU6's
// W6-part (they consume the same tensor). Single self-synchronized chain:
// no cc5 coupling, no separate GRU6 wg set.
// Wave split: w0 GRU5 z+xh (20 frags), w1 GRU5 r+ih (34), w2 GRU6 z+xh (48),
// w3 GRU6 r+ih (48). z@W5 precomputed once (mask folded per step, bilinear).
// Sync: h words u32=(tag<<16)|bf16, relaxed agent atomics, bulk-parallel
// retry. h5[s]/h6[s] at slot s&3, tag s+1 (0 = zero init). 4-slot WAR safety
// via tag-observation data dependency (observing h5[t-1]/h6[t-2] tags =>
// all peers >= step t-1 => nobody reads the slot being overwritten).
// Iter t (0..513): poll h6[t-2] (t>=1), poll h5[t-1] (t<=512), stage;
// compute h5[t] (t<512), h6[t-1] (1<=t<=512), dec[t-2] (t>=2, sl<16, w0).

__device__ __forceinline__ u16 f2bf(float f) {
    u32 u = __float_as_uint(f);
    u32 r = (u + 0x7fffu + ((u >> 16) & 1u)) >> 16;
    return (u16)r;
}
__device__ __forceinline__ float bf2f(u16 v) { return __uint_as_float(((u32)v) << 16); }
__device__ __forceinline__ float sat01(float x) { return fminf(1.f, fmaxf(0.f, x)); }
__device__ __forceinline__ float ftanh(float x) {
    x = fminf(10.f, fmaxf(-10.f, x));
    float e = __expf(2.f * x);
    return (e - 1.f) / (e + 1.f);
}

__device__ __forceinline__ bf16x8 loadB(const float* __restrict__ M, int k0, int colbase,
                                        int l15, int q8) {
    const float* p = M + (size_t)(k0 + q8) * 1536 + colbase + l15;
    bf16x8 r;
#pragma unroll
    for (int j = 0; j < 8; ++j) r[j] = (short)f2bf(p[(size_t)j * 1536]);
    return r;
}

#define ST 1096           // stg row stride (u16): 64 x2 | 512 h5 | 512 h6 | 8 pad
#define H5OFF 64
#define H6OFF 576

__device__ __forceinline__ bf16x8 ldsA(const u16* s, int off, int l15, int q8) {
    return *(const bf16x8*)(s + l15 * ST + off + q8);
}

__global__ void zero_ws_kernel(u32* ws) {
    int i = blockIdx.x * 256 + threadIdx.x;
    if (i < 524288) ws[i] = 0u;  // h5w[4][128][512] + h6w[4][128][512]
}

__global__ void __launch_bounds__(256, 1)
gru_fused(const float* __restrict__ zin, const float* __restrict__ x2,
          const float* __restrict__ msk, const float* __restrict__ dmsk,
          const float* __restrict__ W5, const float* __restrict__ U5,
          const float* __restrict__ bi5, const float* __restrict__ br5,
          const float* __restrict__ W6, const float* __restrict__ U6,
          const float* __restrict__ bi6, const float* __restrict__ br6,
          const float* __restrict__ Wd, const float* __restrict__ bdp,
          float* __restrict__ out, u32* __restrict__ h5w,
          u32* __restrict__ h6w)
{
    const int wg = blockIdx.x;
    const int rgp = wg & 7;            // rowgroup (XCD-local under round-robin)
    const int sl = wg >> 3;            // 0..31: 16-col slice
    const int row0 = rgp << 4;
    const int sb = sl << 4;            // col base (0..496)
    const int tid = threadIdx.x;
    const int wv = tid >> 6, lane = tid & 63;
    const int l15 = lane & 15, q8 = (lane >> 4) << 3;

    __shared__ u16 stg[16 * ST];
    __shared__ float exch[8 * 272];    // z5,r5,xh5,ih5,z6,r6,xh6,ih6
    __shared__ float mkl[16];

    // per-wave gate columns and biases
    // w0: z5(sb), xh5(1024+sb)   w1: r5(512+sb), ih5(1024+sb)
    // w2: z6(sb), xh6(1024+sb)   w3: r6(512+sb), ih6(1024+sb)
    const int gsel = wv & 1;                 // 0: z-pair, 1: r-pair
    const bool lay6 = wv >= 2;
    const int colM = gsel * 512 + sb;
    const int colS = 1024 + sb;
    const float* bi = lay6 ? bi6 : bi5;
    const float* br = lay6 ? br6 : br5;
    const float biasM = bi[colM + l15] + br[colM + l15];
    const float biasS = (gsel == 0) ? bi[colS + l15] : br[colS + l15];

    // ---- persistent B fragments ----
    bf16x8 Ba[16], Bb[16], Bc[16];
    if (wv == 0) {
#pragma unroll
        for (int kt = 0; kt < 2; ++kt)  Ba[kt] = loadB(W5, 256 + kt * 32, sb, l15, q8);
#pragma unroll
        for (int kt = 0; kt < 16; ++kt) Bb[kt] = loadB(U5, kt * 32, sb, l15, q8);
#pragma unroll
        for (int kt = 0; kt < 2; ++kt)  Bc[kt] = loadB(W5, 256 + kt * 32, 1024 + sb, l15, q8);
    } else if (wv == 1) {
#pragma unroll
        for (int kt = 0; kt < 2; ++kt)  Ba[kt] = loadB(W5, 256 + kt * 32, 512 + sb, l15, q8);
#pragma unroll
        for (int kt = 0; kt < 16; ++kt) Bb[kt] = loadB(U5, kt * 32, 512 + sb, l15, q8);
#pragma unroll
        for (int kt = 0; kt < 16; ++kt) Bc[kt] = loadB(U5, kt * 32, 1024 + sb, l15, q8);
    } else if (wv == 2) {
#pragma unroll
        for (int kt = 0; kt < 16; ++kt) Ba[kt] = loadB(W6, kt * 32, sb, l15, q8);
#pragma unroll
        for (int kt = 0; kt < 16; ++kt) Bb[kt] = loadB(U6, kt * 32, sb, l15, q8);
#pragma unroll
        for (int kt = 0; kt < 16; ++kt) Bc[kt] = loadB(W6, kt * 32, 1024 + sb, l15, q8);
    } else {
#pragma unroll
        for (int kt = 0; kt < 16; ++kt) Ba[kt] = loadB(W6, kt * 32, 512 + sb, l15, q8);
#pragma unroll
        for (int kt = 0; kt < 16; ++kt) Bb[kt] = loadB(U6, kt * 32, 512 + sb, l15, q8);
#pragma unroll
        for (int kt = 0; kt < 16; ++kt) Bc[kt] = loadB(U6, kt * 32, 1024 + sb, l15, q8);
    }

    // dec weights: wgs sl<16 emit dec for batch row (row0+sl); wave 0 does it
    float wdv[8]; float bdv = bdp[0];
    if (sl < 16 && wv == 0) {
#pragma unroll
        for (int j = 0; j < 8; ++j) wdv[j] = Wd[lane * 8 + j];
    }

    const int r_ = tid >> 4, cth = tid & 15;   // staging/gating coords
    const int b_ = row0 + r_;

    // ---- one-time z@W5 precompute (w0, w1 use it) ----
    for (int c = cth; c < 256; c += 16) stg[r_ * ST + H5OFF + c] = f2bf(zin[b_ * 256 + c]);
    __syncthreads();
    f32x4 zaccM = {0.f, 0.f, 0.f, 0.f}, zaccS = {0.f, 0.f, 0.f, 0.f};
    if (wv < 2) {
        for (int kt = 0; kt < 8; ++kt) {
            bf16x8 a = ldsA(stg, H5OFF + kt * 32, l15, q8);
            zaccM = MFMA(a, loadB(W5, kt * 32, colM, l15, q8), zaccM);
            if (wv == 0)
                zaccS = MFMA(a, loadB(W5, kt * 32, 1024 + sb, l15, q8), zaccS);
        }
    }
    __syncthreads();

    // fp32 master h states: thread owns (row=r_, col=cth) of the 16x16 tile
    float hold5 = 0.f, hold6 = 0.f;

    for (int t = 0; t < 514; ++t) {
        // ================== phase A: polls + staging ==================
        u64 v[16];
        if (t >= 1) {   // h6[t-2]: slot (t-2)&3, tag t-1 (old -> usually 1 round)
            const u64* s2 = (const u64*)(h6w + ((t + 2) & 3) * 65536) + (size_t)b_ * 256;
            const u32 exp2 = (u32)(t - 1);
#pragma unroll
            for (int k = 0; k < 16; ++k)
                v[k] = __hip_atomic_load(&s2[cth + 16 * k], __ATOMIC_RELAXED, AGENT);
            for (;;) {
                bool ok = true;
#pragma unroll
                for (int k = 0; k < 16; ++k) {
                    u32 lo = (u32)v[k], hi = (u32)(v[k] >> 32);
                    if (((lo >> 16) != exp2) | ((hi >> 16) != exp2)) ok = false;
                }
                if (ok) break;
                __builtin_amdgcn_s_sleep(1);
#pragma unroll
                for (int k = 0; k < 16; ++k)
                    v[k] = __hip_atomic_load(&s2[cth + 16 * k], __ATOMIC_RELAXED, AGENT);
            }
#pragma unroll
            for (int k = 0; k < 16; ++k) {
                u32 lo = (u32)v[k], hi = (u32)(v[k] >> 32);
                *(u32*)&stg[r_ * ST + H6OFF + 2 * (cth + 16 * k)] = (lo & 0xffffu) | (hi << 16);
            }
        }
        if (t <= 512) {  // h5[t-1]: slot (t-1)&3, tag t (fresh -> the real wait)
            const u64* s1 = (const u64*)(h5w + ((t + 3) & 3) * 65536) + (size_t)b_ * 256;
            const u32 exp1 = (u32)t;
#pragma unroll
            for (int k = 0; k < 16; ++k)
                v[k] = __hip_atomic_load(&s1[cth + 16 * k], __ATOMIC_RELAXED, AGENT);
            // stage x2*mk + mkl under the poll latency
            if (t < 512) {
                float mk = msk[b_ * 512 + t];
#pragma unroll
                for (int i = 0; i < 4; ++i) {
                    int c = cth + 16 * i;
                    stg[r_ * ST + c] = f2bf(x2[(b_ * 512 + t) * 64 + c] * mk);
                }
                if (tid < 16) mkl[tid] = msk[(row0 + tid) * 512 + t];
            }
            for (;;) {
                bool ok = true;
#pragma unroll
                for (int k = 0; k < 16; ++k) {
                    u32 lo = (u32)v[k], hi = (u32)(v[k] >> 32);
                    if (((lo >> 16) != exp1) | ((hi >> 16) != exp1)) ok = false;
                }
                if (ok) break;
                __builtin_amdgcn_s_sleep(1);
#pragma unroll
                for (int k = 0; k < 16; ++k)
                    v[k] = __hip_atomic_load(&s1[cth + 16 * k], __ATOMIC_RELAXED, AGENT);
            }
#pragma unroll
            for (int k = 0; k < 16; ++k) {
                u32 lo = (u32)v[k], hi = (u32)(v[k] >> 32);
                *(u32*)&stg[r_ * ST + H5OFF + 2 * (cth + 16 * k)] = (lo & 0xffffu) | (hi << 16);
            }
        }
        __syncthreads();   // S1: staged

        // ================== phase B: MFMA + exch + dec ==================
        const bool do5 = (t < 512);              // compute h5[t]
        const bool do6 = (t >= 1 && t <= 512);   // compute h6[t-1]
        f32x4 a0, a1;
        if (!lay6 && do5) {
            float mkr[4];
#pragma unroll
            for (int i = 0; i < 4; ++i) mkr[i] = mkl[(lane >> 4) * 4 + i];
#pragma unroll
            for (int i = 0; i < 4; ++i) a0[i] = biasM + mkr[i] * zaccM[i];
            if (wv == 0) {
#pragma unroll
                for (int i = 0; i < 4; ++i) a1[i] = biasS + mkr[i] * zaccS[i];
#pragma unroll
                for (int kt = 0; kt < 2; ++kt) {
                    bf16x8 a = ldsA(stg, kt * 32, l15, q8);
                    a0 = MFMA(a, Ba[kt], a0);
                    a1 = MFMA(a, Bc[kt], a1);
                }
#pragma unroll
                for (int kt = 0; kt < 16; ++kt)
                    a0 = MFMA(ldsA(stg, H5OFF + kt * 32, l15, q8), Bb[kt], a0);
            } else {
#pragma unroll
                for (int i = 0; i < 4; ++i) a1[i] = biasS;
#pragma unroll
                for (int kt = 0; kt < 2; ++kt)
                    a0 = MFMA(ldsA(stg, kt * 32, l15, q8), Ba[kt], a0);
#pragma unroll
                for (int kt = 0; kt < 16; ++kt) {
                    bf16x8 a = ldsA(stg, H5OFF + kt * 32, l15, q8);
                    a0 = MFMA(a, Bb[kt], a0);
                    a1 = MFMA(a, Bc[kt], a1);
                }
            }
        }
        if (lay6 && do6) {
#pragma unroll
            for (int i = 0; i < 4; ++i) { a0[i] = biasM; a1[i] = biasS; }
            if (wv == 2) {
#pragma unroll
                for (int kt = 0; kt < 16; ++kt) {
                    bf16x8 a = ldsA(stg, H5OFF + kt * 32, l15, q8);
                    a0 = MFMA(a, Ba[kt], a0);
                    a1 = MFMA(a, Bc[kt], a1);
                }
#pragma unroll
                for (int kt = 0; kt < 16; ++kt)
                    a0 = MFMA(ldsA(stg, H6OFF + kt * 32, l15, q8), Bb[kt], a0);
            } else {
#pragma unroll
                for (int kt = 0; kt < 16; ++kt)
                    a0 = MFMA(ldsA(stg, H5OFF + kt * 32, l15, q8), Ba[kt], a0);
#pragma unroll
                for (int kt = 0; kt < 16; ++kt) {
                    bf16x8 a = ldsA(stg, H6OFF + kt * 32, l15, q8);
                    a0 = MFMA(a, Bb[kt], a0);
                    a1 = MFMA(a, Bc[kt], a1);
                }
            }
        }
        // exch: w0->(0,2) w1->(1,3) w2->(4,6) w3->(5,7)
        if ((!lay6 && do5) || (lay6 && do6)) {
            int uM = (lay6 ? 4 : 0) + gsel;
            int uS = (lay6 ? 6 : 2) + gsel;
#pragma unroll
            for (int i = 0; i < 4; ++i) {
                int rr = (lane >> 4) * 4 + i;
                exch[uM * 272 + rr * 17 + l15] = a0[i];
                exch[uS * 272 + rr * 17 + l15] = a1[i];
            }
        }
        // dec[t-2] from staged h6[t-2] (w0 of wgs sl<16; reads stg H6OFF)
        if (t >= 2 && wv == 0 && sl < 16) {
            const u16* hrow = &stg[sl * ST + H6OFF + lane * 8];
            bf16x8 hv = *(const bf16x8*)hrow;
            float s = 0.f;
#pragma unroll
            for (int j = 0; j < 8; ++j) s += bf2f((u16)hv[j]) * wdv[j];
#pragma unroll
            for (int off = 32; off >= 1; off >>= 1) s += __shfl_down(s, off);
            if (lane == 0) {
                int tt = t - 2;
                out[(row0 + sl) * 512 + tt] = ftanh(s + bdv) * dmsk[(row0 + sl) * 512 + tt];
            }
        }
        __syncthreads();   // S2: exch ready

        // ================== phase C: gate combine + tagged stores ==================
        if (do5) {
            float zv = exch[0 * 272 + r_ * 17 + cth];
            float rv = exch[1 * 272 + r_ * 17 + cth];
            float xh = exch[2 * 272 + r_ * 17 + cth];
            float ih = exch[3 * 272 + r_ * 17 + cth];
            float zg = sat01(0.2f * zv + 0.5f);
            float rg = sat01(0.2f * rv + 0.5f);
            float hh = ftanh(xh + rg * ih);
            float hn = zg * hold5 + (1.f - zg) * hh;
            hold5 = hn;
            u32 w = ((u32)(t + 1) << 16) | (u32)f2bf(hn);
            __hip_atomic_store(&h5w[(t & 3) * 65536 + b_ * 512 + sb + cth], w,
                               __ATOMIC_RELAXED, AGENT);
        }
        if (do6) {
            float zv = exch[4 * 272 + r_ * 17 + cth];
            float rv = exch[5 * 272 + r_ * 17 + cth];
            float xh = exch[6 * 272 + r_ * 17 + cth];
            float ih = exch[7 * 272 + r_ * 17 + cth];
            float zg = sat01(0.2f * zv + 0.5f);
            float rg = sat01(0.2f * rv + 0.5f);
            float hh = ftanh(xh + rg * ih);
            float hn = zg * hold6 + (1.f - zg) * hh;
            hold6 = hn;
            u32 w = ((u32)t << 16) | (u32)f2bf(hn);   // h6[t-1] tag t, slot (t-1)&3
            __hip_atomic_store(&h6w[((t + 3) & 3) * 65536 + b_ * 512 + sb + cth], w,
                               __ATOMIC_RELAXED, AGENT);
        }
    }
}

extern "C" void kernel_launch(void* const* d_in, const int* in_sizes, int n_in,
                              void* d_out, int out_size, void* d_ws, size_t ws_size,
                              hipStream_t stream) {
    const float* zin = (const float*)d_in[0];
    const float* x2  = (const float*)d_in[1];
    const float* msk = (const float*)d_in[2];
    const float* dmk = (const float*)d_in[3];
    const float* W5  = (const float*)d_in[4];
    const float* U5  = (const float*)d_in[5];
    const float* bi5 = (const float*)d_in[6];
    const float* br5 = (const float*)d_in[7];
    const float* W6  = (const float*)d_in[8];
    const float* U6  = (const float*)d_in[9];
    const float* bi6 = (const float*)d_in[10];
    const float* br6 = (const float*)d_in[11];
    const float* Wd  = (const float*)d_in[12];
    const float* bd  = (const float*)d_in[13];
    float* out = (float*)d_out;

    // ws (u32): h5w[4][128][512] | h6w[4][128][512]   (2 MB)
    u32* h5w = (u32*)d_ws;
    u32* h6w = h5w + 262144;

    zero_ws_kernel<<<dim3(2048), dim3(256), 0, stream>>>((u32*)d_ws);

    gru_fused<<<dim3(256), dim3(256), 0, stream>>>(
        zin, x2, msk, dmk, W5, U5, bi5, br5, W6, U6, bi6, br6,
        Wd, bd, out, h5w, h6w);
}